// Round 2
// baseline (7442.345 us; speedup 1.0000x reference)
//
#include <hip/hip_runtime.h>
#include <hip/hip_bf16.h>
#include <stdint.h>

// Problem constants
#define B_   32
#define N_   2048   // n_stock
#define F_   1024   // in_features
#define HS_  8192   // 4*N
#define HF_  4096   // 4*F
#define OUT_ 1024

typedef __bf16 bf16x8 __attribute__((ext_vector_type(8)));
typedef float  f32x4  __attribute__((ext_vector_type(4)));

__device__ __forceinline__ float bf2f(unsigned short u) {
  union { unsigned int i; float f; } c; c.i = ((unsigned int)u) << 16; return c.f;
}
__device__ __forceinline__ unsigned short f2bf(float f) {
  union { float f; unsigned int i; } c; c.f = f;
  unsigned int x = c.i;
  return (unsigned short)((x + 0x7FFFu + ((x >> 16) & 1u)) >> 16);  // RNE
}

// ---------------------------------------------------------------------------
// 0. f32 -> bf16 bulk convert (weights). n multiple of 8.
// ---------------------------------------------------------------------------
__global__ __launch_bounds__(256) void f2bf_kernel(
    const float* __restrict__ in, unsigned short* __restrict__ out, int n) {
  int i = (blockIdx.x * 256 + threadIdx.x) * 8;
  if (i >= n) return;
  const float4 a = ((const float4*)(in + i))[0];
  const float4 b = ((const float4*)(in + i))[1];
  unsigned int w0 = (unsigned int)f2bf(a.x) | ((unsigned int)f2bf(a.y) << 16);
  unsigned int w1 = (unsigned int)f2bf(a.z) | ((unsigned int)f2bf(a.w) << 16);
  unsigned int w2 = (unsigned int)f2bf(b.x) | ((unsigned int)f2bf(b.y) << 16);
  unsigned int w3 = (unsigned int)f2bf(b.z) | ((unsigned int)f2bf(b.w) << 16);
  *(uint4*)(out + i) = make_uint4(w0, w1, w2, w3);
}

// ---------------------------------------------------------------------------
// 1. Transpose x [B,N,F] -> xm [B,F,N]  (f32, LDS 64x64 tile, +1 pad)
// ---------------------------------------------------------------------------
__global__ __launch_bounds__(256) void transpose_xk(
    const float* __restrict__ x, float* __restrict__ xm) {
  __shared__ float tile[64][65];
  const int b  = blockIdx.z;
  const int n0 = blockIdx.y * 64;
  const int f0 = blockIdx.x * 64;
  const int tx = threadIdx.x & 63;
  const int ty = threadIdx.x >> 6;
  const float* xp = x + ((size_t)b * N_ + n0) * F_ + f0;
  #pragma unroll
  for (int r = 0; r < 16; ++r) {
    int n = ty + r * 4;
    tile[tx][n] = xp[(size_t)n * F_ + tx];   // tile[f][n]
  }
  __syncthreads();
  float* xmp = xm + ((size_t)b * F_ + f0) * N_ + n0;
  #pragma unroll
  for (int r = 0; r < 16; ++r) {
    int f = ty + r * 4;
    xmp[(size_t)f * N_ + tx] = tile[f][tx];
  }
}

// ---------------------------------------------------------------------------
// 2. Stable argsort per (b,f) row of f32 xm; emit xs (bf16) and inv (u16).
//    u64 key = (order-preserving f32 map << 32) | idx  -> stable ascending.
//    xs[j] = xm[inv[j]] (scatter-by-argsort == gather-by-inverse).
// ---------------------------------------------------------------------------
__global__ __launch_bounds__(256) void sort_kernel(
    const float* __restrict__ xm,
    unsigned short* __restrict__ xs,
    unsigned short* __restrict__ inv) {
  __shared__ unsigned long long keys[N_];   // 16 KB
  __shared__ float          vals[N_];       // 8 KB
  __shared__ unsigned short invs[N_];       // 4 KB
  const int t = threadIdx.x;
  const size_t rb = (size_t)blockIdx.x * N_;
  const float4* r4 = (const float4*)(xm + rb);

  #pragma unroll
  for (int h = 0; h < 2; ++h) {
    const float4 v = r4[t + h * 256];
    const int base = (t + h * 256) * 4;
    float f[4] = {v.x, v.y, v.z, v.w};
    #pragma unroll
    for (int e = 0; e < 4; ++e) {
      union { float f; unsigned int i; } c; c.f = f[e];
      unsigned int m = (c.i & 0x80000000u) ? ~c.i : (c.i | 0x80000000u);
      keys[base + e] = (((unsigned long long)m) << 32) | (unsigned long long)(base + e);
      vals[base + e] = f[e];
    }
  }
  __syncthreads();

  for (int k = 2; k <= N_; k <<= 1) {
    for (int j = k >> 1; j > 0; j >>= 1) {
      #pragma unroll 4
      for (int i = t; i < N_; i += 256) {
        int l = i ^ j;
        if (l > i) {
          unsigned long long a = keys[i], c = keys[l];
          bool up = ((i & k) == 0);
          if ((a > c) == up) { keys[i] = c; keys[l] = a; }
        }
      }
      __syncthreads();
    }
  }
  #pragma unroll
  for (int i = t; i < N_; i += 256)
    invs[(unsigned int)(keys[i] & 0xFFFFu)] = (unsigned short)i;
  __syncthreads();
  unsigned short* xsr  = xs  + rb;
  unsigned short* invr = inv + rb;
  #pragma unroll
  for (int i = t; i < N_; i += 256) {
    unsigned short iv = invs[i];
    xsr[i]  = f2bf(vals[iv]);
    invr[i] = iv;
  }
}

// ---------------------------------------------------------------------------
// 3. NT GEMM (m97 recipe): C[M,N] = A[M,K] * Bt[N,K]^T, bf16 in, fp32 acc.
//    128x128 tile, BK=64, global_load_lds(16B), 16x16x32 bf16 MFMA.
//    EPI: 0 = bias+relu -> bf16, 1 = bias+skip(bf16) -> bf16, 2 = bias -> f32
// ---------------------------------------------------------------------------
template <int EPI>
__global__ __launch_bounds__(256) void gemm_bt(
    const unsigned short* __restrict__ A,
    const unsigned short* __restrict__ Bt,
    const float* __restrict__ bias,
    const unsigned short* __restrict__ skip,
    void* __restrict__ Cv,
    int N, int K) {
  __shared__ __align__(16) unsigned short As[128 * 64];
  __shared__ __align__(16) unsigned short Bs[128 * 64];
  const int n0   = blockIdx.x * 128;
  const int m0   = blockIdx.y * 128;
  const int t    = threadIdx.x;
  const int lane = t & 63;
  const int wave = t >> 6;
  const int wm = (wave >> 1) * 64;
  const int wn = (wave & 1) * 64;
  const int lr = lane & 15;
  const int lk = (lane >> 4) * 8;

  f32x4 acc[4][4];
  #pragma unroll
  for (int i = 0; i < 4; ++i)
    #pragma unroll
    for (int j = 0; j < 4; ++j)
      acc[i][j] = (f32x4){0.f, 0.f, 0.f, 0.f};

  const unsigned short* aB = A  + (size_t)m0 * K;
  const unsigned short* bB = Bt + (size_t)n0 * K;

  for (int k0 = 0; k0 < K; k0 += 64) {
    #pragma unroll
    for (int i = 0; i < 4; ++i) {
      const int cbase = i * 256 + wave * 64;       // wave-uniform LDS base chunk
      const int chunk = cbase + lane;
      const int row = chunk >> 3;
      const int col = (chunk & 7) << 3;            // element offset (8 bf16 = 16B)
      __builtin_amdgcn_global_load_lds(
          (const __attribute__((address_space(1))) void*)(aB + (size_t)row * K + (k0 + col)),
          (__attribute__((address_space(3))) void*)(As + (size_t)cbase * 8), 16, 0, 0);
      __builtin_amdgcn_global_load_lds(
          (const __attribute__((address_space(1))) void*)(bB + (size_t)row * K + (k0 + col)),
          (__attribute__((address_space(3))) void*)(Bs + (size_t)cbase * 8), 16, 0, 0);
    }
    __syncthreads();
    #pragma unroll
    for (int kk = 0; kk < 64; kk += 32) {
      bf16x8 af[4], bv[4];
      #pragma unroll
      for (int i = 0; i < 4; ++i)
        af[i] = *(const bf16x8*)(As + (wm + i * 16 + lr) * 64 + kk + lk);
      #pragma unroll
      for (int j = 0; j < 4; ++j)
        bv[j] = *(const bf16x8*)(Bs + (wn + j * 16 + lr) * 64 + kk + lk);
      #pragma unroll
      for (int i = 0; i < 4; ++i)
        #pragma unroll
        for (int j = 0; j < 4; ++j)
          acc[i][j] = __builtin_amdgcn_mfma_f32_16x16x32_bf16(af[i], bv[j], acc[i][j], 0, 0, 0);
    }
    __syncthreads();
  }

  // epilogue: C/D layout col=lane&15, row=(lane>>4)*4+reg  [m89-verified]
  #pragma unroll
  for (int j = 0; j < 4; ++j) {
    const int gn = n0 + wn + j * 16 + lr;
    const float bvf = bias[gn];
    #pragma unroll
    for (int i = 0; i < 4; ++i) {
      const int gm = m0 + wm + i * 16 + (lane >> 4) * 4;
      #pragma unroll
      for (int r = 0; r < 4; ++r) {
        float v = acc[i][j][r] + bvf;
        if (EPI == 0) v = v > 0.f ? v : 0.f;
        const size_t off = (size_t)(gm + r) * N + gn;
        if (EPI == 1) v += bf2f(skip[off]);
        if (EPI == 2) ((float*)Cv)[off] = v;
        else          ((unsigned short*)Cv)[off] = f2bf(v);
      }
    }
  }
}

// ---------------------------------------------------------------------------
// 4. Unpermute + transpose: Y2[b, inv[b,f,j], f] = Y[b, f, j]   (bf16)
// ---------------------------------------------------------------------------
__global__ __launch_bounds__(256) void unpermute_kernel(
    const unsigned short* __restrict__ Y,
    const unsigned short* __restrict__ inv,
    unsigned short* __restrict__ Y2) {
  __shared__ unsigned short ot[N_][16];      // 64 KB, col swizzle (fl + (n>>2)) & 15
  const int b  = blockIdx.x >> 6;            // F/16 = 64 slabs per batch
  const int f0 = (blockIdx.x & 63) * 16;
  const int t  = threadIdx.x;
  const size_t rbase = ((size_t)b * F_ + f0) * N_;

  for (int fl = 0; fl < 16; ++fl) {
    const uint4 yv = ((const uint4*)(Y   + rbase + (size_t)fl * N_))[t];
    const uint4 iv = ((const uint4*)(inv + rbase + (size_t)fl * N_))[t];
    unsigned int yw[4] = {yv.x, yv.y, yv.z, yv.w};
    unsigned int iw[4] = {iv.x, iv.y, iv.z, iv.w};
    #pragma unroll
    for (int e = 0; e < 8; ++e) {
      unsigned short yy = (unsigned short)(yw[e >> 1] >> ((e & 1) * 16));
      int n = (int)(unsigned short)(iw[e >> 1] >> ((e & 1) * 16));
      ot[n][(fl + (n >> 2)) & 15] = yy;
    }
  }
  __syncthreads();
  unsigned short* o = Y2 + (size_t)b * N_ * F_ + f0;
  for (int it = 0; it < 8; ++it) {
    int n = it * 256 + t;
    unsigned short tmp[16];
    #pragma unroll
    for (int fl = 0; fl < 16; ++fl) tmp[fl] = ot[n][(fl + (n >> 2)) & 15];
    unsigned int pw[8];
    #pragma unroll
    for (int q = 0; q < 8; ++q)
      pw[q] = (unsigned int)tmp[2 * q] | (((unsigned int)tmp[2 * q + 1]) << 16);
    uint4* dst = (uint4*)(o + (size_t)n * F_);
    dst[0] = make_uint4(pw[0], pw[1], pw[2], pw[3]);
    dst[1] = make_uint4(pw[4], pw[5], pw[6], pw[7]);
  }
}

// ---------------------------------------------------------------------------
extern "C" void kernel_launch(void* const* d_in, const int* in_sizes, int n_in,
                              void* d_out, int out_size, void* d_ws, size_t ws_size,
                              hipStream_t stream) {
  const float* x    = (const float*)d_in[0];
  const float* sw1f = (const float*)d_in[1];
  const float* sb1  = (const float*)d_in[2];
  const float* sw2f = (const float*)d_in[3];
  const float* sb2  = (const float*)d_in[4];
  const float* fw1f = (const float*)d_in[5];
  const float* fb1  = (const float*)d_in[6];
  const float* fw2f = (const float*)d_in[7];
  const float* fb2  = (const float*)d_in[8];
  float* outp = (float*)d_out;

  const size_t E = (size_t)B_ * F_ * N_;     // 67,108,864 elements
  // workspace layout (~730 MB)
  float*          xm  = (float*)d_ws;                     // E f32      [0, 256MB)
  unsigned short* xs  = (unsigned short*)(xm + E);        // E bf16     [256, 384)
  unsigned short* inv = xs + E;                           // E u16      [384, 512)
  unsigned short* wb  = inv + E;                          // weights bf16
  unsigned short* wsw1 = wb;                              // 8192*2048
  unsigned short* wsw2 = wsw1 + (size_t)HS_ * N_;         // 2048*8192
  unsigned short* wfw1 = wsw2 + (size_t)N_ * HS_;         // 4096*1024
  unsigned short* wfw2 = wfw1 + (size_t)HF_ * F_;         // 1024*4096
  unsigned short* Hc   = wfw2 + (size_t)OUT_ * HF_;       // 67.1M bf16 (134 MB) chunk hidden
  unsigned short* Y    = (unsigned short*)xm;             // reuse xm region (bf16)
  unsigned short* Y2   = xs;                              // reuse xs region

  // 0. convert weights f32 -> bf16
  f2bf_kernel<<<(HS_ * N_) / 2048, 256, 0, stream>>>(sw1f, wsw1, HS_ * N_);
  f2bf_kernel<<<(N_ * HS_) / 2048, 256, 0, stream>>>(sw2f, wsw2, N_ * HS_);
  f2bf_kernel<<<(HF_ * F_) / 2048, 256, 0, stream>>>(fw1f, wfw1, HF_ * F_);
  f2bf_kernel<<<(OUT_ * HF_) / 2048, 256, 0, stream>>>(fw2f, wfw2, OUT_ * HF_);

  // 1. transpose x -> xm (f32)
  transpose_xk<<<dim3(F_ / 64, N_ / 64, B_), 256, 0, stream>>>(x, xm);
  // 2. stable sort rows -> xs (bf16), inv (u16)
  sort_kernel<<<dim3(B_ * F_), 256, 0, stream>>>(xm, xs, inv);

  // 3+4. sorted MLP, chunked over rows (4 x 8192 rows)
  for (int c = 0; c < 4; ++c) {
    const size_t ro = (size_t)c * 8192;
    gemm_bt<0><<<dim3(HS_ / 128, 8192 / 128), 256, 0, stream>>>(
        xs + ro * N_, wsw1, sb1, nullptr, Hc, HS_, N_);
    gemm_bt<1><<<dim3(N_ / 128, 8192 / 128), 256, 0, stream>>>(
        Hc, wsw2, sb2, xs + ro * N_, Y + ro * N_, N_, HS_);
  }

  // 5. Y2[b, inv[j], f] = Y[b, f, j]
  unpermute_kernel<<<dim3(B_ * (F_ / 16)), 256, 0, stream>>>(Y, inv, Y2);

  // 6+7. feature MLP, chunked over rows (4 x 16384 rows)
  for (int c = 0; c < 4; ++c) {
    const size_t ro = (size_t)c * 16384;
    gemm_bt<0><<<dim3(HF_ / 128, 16384 / 128), 256, 0, stream>>>(
        Y2 + ro * F_, wfw1, fb1, nullptr, Hc, HF_, F_);
    gemm_bt<2><<<dim3(OUT_ / 128, 16384 / 128), 256, 0, stream>>>(
        Hc, wfw2, fb2, nullptr, (void*)(outp + ro * OUT_), OUT_, HF_);
  }
}